// Round 7
// baseline (53.206 us; speedup 1.0000x reference)
//
#include <hip/hip_runtime.h>

// ---- problem constants ----
// B=16, N=512, D_MODEL=256, NUM_RBF=50, CUTOFF=12
// delta = 12/49, width = 2*delta
// S = 2.45229158;  D = delta*S = sqrt(log2 e)/2 = 0.60056098
// Key identity: 4*D^2 = log2(e)  =>  2^{-m*D^2} = e^{-m/4}
// g_k (k = 10c + r, r in [0,10)):
//   u  = dS - 10c*D
//   g  = 2^{-u^2} * (2^{2D*u})^r * e^{-r^2/4} = t0 * Ac^r * e^{-r^2/4}
// Ac = Ap * e^{-5c},  Ap = 2^{2D*dS};  e^{-r^2/4} applied once at the end.
#define S_C     2.45229158f
#define TWO_DS  1.20112241f   /* 2*D */
#define TEN_D   6.00560980f   /* 10*D */
#define E5_1 6.73794700e-3f   /* e^-5  */
#define E5_2 4.53999298e-5f   /* e^-10 */
#define E5_3 3.05902321e-7f   /* e^-15 */
#define E5_4 2.06115362e-9f   /* e^-20 */

typedef float v2f __attribute__((ext_vector_type(2)));

__device__ __forceinline__ float fast_exp2(float x) {
#if __has_builtin(__builtin_amdgcn_exp2f)
    return __builtin_amdgcn_exp2f(x);
#else
    float r;
    asm("v_exp_f32 %0, %1" : "=v"(r) : "v"(x));
    return r;
#endif
}
__device__ __forceinline__ float fast_sqrt(float x) {
#if __has_builtin(__builtin_amdgcn_sqrtf)
    return __builtin_amdgcn_sqrtf(x);
#else
    return sqrtf(x);
#endif
}

// DIAGNOSTIC build of the R5 fused kernel: the neighbor core runs `reps`
// times (host passes 4) with a compiler-opaque zero offset so no pass can
// be hoisted/folded; result scaled by 1/(512*reps). Output is numerically
// equivalent; dispatch duration rises to ~4x core so our kernel finally
// surfaces in the rocprof top-5 with real counters, and
// core_us = (dur(reps=4) - dur(reps=1)) / 3 from the R5 baseline.
__global__ __launch_bounds__(256)
void rbf_fused_kernel(const float* __restrict__ pos,
                      const int* __restrict__ an,
                      const float* __restrict__ te,
                      const float* __restrict__ pw,
                      const float* __restrict__ pb,
                      float* __restrict__ out,
                      int reps, float scale)
{
    __shared__ v2f   red2[4][32 * 25];   // [wave][(lane/2)*25 + m]  25.6 KB
    __shared__ float ms[4][52];          // wave-private mean broadcast

    const int w    = threadIdx.x >> 6;
    const int lane = threadIdx.x & 63;
    const int row  = blockIdx.x * 4 + w;    // 0..8191
    const int b    = row >> 9;              // N = 512
    const int i    = row & 511;

    const float* posb = pos + (size_t)b * 1536;

    const float pix = posb[i * 3 + 0];
    const float piy = posb[i * 3 + 1];
    const float piz = posb[i * 3 + 2];

    v2f acc[25];   // acc[5c+t] = sum {t''_{2t}, t''_{2t+1}} of chunk c
#pragma unroll
    for (int m = 0; m < 25; ++m) acc[m] = (v2f){0.0f, 0.0f};

#pragma unroll 1
    for (int rep = 0; rep < reps; ++rep) {
        // (rep>>2)*96 == 0 for rep<4, but the compiler cannot prove it:
        // keeps every pass's loads + chain live (no LICM / pass folding).
        const float* posr = posb + (rep >> 2) * 96;

#pragma unroll
        for (int jj = 0; jj < 8; ++jj) {
            const float* pj = posr + jj * 192 + lane * 3;
            const float dx = pix - pj[0];
            const float dy = piy - pj[1];
            const float dz = piz - pj[2];
            const float d2 = fmaf(dx, dx, fmaf(dy, dy, fmaf(dz, dz, 1e-8f)));
            float dS = fast_sqrt(d2) * S_C;
            dS = fminf(dS, 42.0f);            // true values identically 0 beyond
            const float Ap = fast_exp2(dS * TWO_DS);   // 2^{2D*dS} <= 2^50.5

#pragma unroll
            for (int c = 0; c < 5; ++c) {
                const float u  = dS - (float)c * TEN_D;
                const float t0 = fast_exp2(-(u * u));
                const float Ac  = (c == 0) ? Ap :
                                  (c == 1) ? Ap * E5_1 :
                                  (c == 2) ? Ap * E5_2 :
                                  (c == 3) ? Ap * E5_3 : Ap * E5_4;
                const float Ac2 = Ac * Ac;    // <= 2^101, finite
                v2f g = {t0, t0 * Ac};
                acc[5 * c + 0] += g;
                const v2f M = {Ac2, Ac2};
#pragma unroll
                for (int t = 1; t < 5; ++t) {
                    g = g * M;
                    acc[5 * c + t] += g;
                }
            }
        }
    }

    // j-independent e^{-r^2/4} factors (r = 2t, 2t+1)
    {
        const v2f QP[5] = {{1.0f,            0.778800783f},
                           {0.367879441f,    0.105399225f},
                           {1.83156389e-2f,  1.93045414e-3f},
                           {1.23409804e-4f,  4.78511739e-6f},
                           {1.12535175e-7f,  1.60522806e-9f}};
#pragma unroll
        for (int m = 0; m < 25; ++m) acc[m] = acc[m] * QP[m % 5];
    }

    // pair-reduce via shfl_xor(1); even lanes write the 32x25-v2f LDS matrix
#pragma unroll
    for (int m = 0; m < 25; ++m) {
        const float lx = __shfl_xor(acc[m].x, 1);
        const float ly = __shfl_xor(acc[m].y, 1);
        acc[m] += (v2f){lx, ly};
    }
    if ((lane & 1) == 0) {
        v2f* myrow = &red2[w][(lane >> 1) * 25];
#pragma unroll
        for (int m = 0; m < 25; ++m) myrow[m] = acc[m];
    }
    // wave-private LDS: in-wave lgkmcnt ordering suffices, no barrier

    if (lane < 50) {
        const float* col = (const float*)&red2[w][0] + lane;
        float s0 = 0.f, s1 = 0.f, s2 = 0.f, s3 = 0.f;
#pragma unroll
        for (int r = 0; r < 32; r += 4) {
            s0 += col[(r + 0) * 50];
            s1 += col[(r + 1) * 50];
            s2 += col[(r + 2) * 50];
            s3 += col[(r + 3) * 50];
        }
        ms[w][lane] = ((s0 + s1) + (s2 + s3)) * scale;
    }

    // ---- fused projection epilogue (wave-private) ----
    const int tok = an[row];                 // wave-uniform -> scalar load
    float4 o = reinterpret_cast<const float4*>(pb)[lane];
    const float4 t = reinterpret_cast<const float4*>(te + (size_t)tok * 256)[lane];
    o.x += t.x; o.y += t.y; o.z += t.z; o.w += t.w;
#pragma unroll
    for (int k = 0; k < 50; ++k) {
        const float mk = ms[w][k];           // uniform LDS broadcast
        const float4 w4 = reinterpret_cast<const float4*>(pw + k * 256)[lane];
        o.x = fmaf(mk, w4.x, o.x);
        o.y = fmaf(mk, w4.y, o.y);
        o.z = fmaf(mk, w4.z, o.z);
        o.w = fmaf(mk, w4.w, o.w);
    }
    reinterpret_cast<float4*>(out)[(size_t)row * 64 + lane] = o;
}

extern "C" void kernel_launch(void* const* d_in, const int* in_sizes, int n_in,
                              void* d_out, int out_size, void* d_ws, size_t ws_size,
                              hipStream_t stream)
{
    const int*   an  = (const int*)  d_in[0];   // [16,512] int32
    const float* pos = (const float*)d_in[1];   // [16,512,3]
    const float* te  = (const float*)d_in[2];   // [100,256]
    const float* pw  = (const float*)d_in[3];   // [50,256]
    const float* pb  = (const float*)d_in[4];   // [256]
    float* out = (float*)d_out;                  // [16,512,256]

    const int   reps  = 4;                       // diagnostic multiplier
    const float scale = 1.0f / (512.0f * (float)reps);
    rbf_fused_kernel<<<2048, 256, 0, stream>>>(pos, an, te, pw, pb, out, reps, scale);
}

// Round 8
// 28.712 us; speedup vs baseline: 1.8531x; 1.8531x over previous
//
#include <hip/hip_runtime.h>

// ---- problem constants ----
// B=16, N=512, D_MODEL=256, NUM_RBF=50, CUTOFF=12
// delta = 12/49, width = 2*delta
// S = 2.45229158;  D = delta*S = sqrt(log2 e)/2 = 0.60056098
// Key identity: 4*D^2 = log2(e)  =>  2^{-m*D^2} = e^{-m/4}
// g_k (k = 10c + r, r in [0,10)):
//   u  = dS - 10c*D
//   g  = 2^{-u^2} * (2^{2D*u})^r * e^{-r^2/4} = t0 * Ac^r * e^{-r^2/4}
// Ac = Ap * e^{-5c},  Ap = 2^{2D*dS};  e^{-r^2/4} applied once at the end.
#define S_C     2.45229158f
#define TWO_DS  1.20112241f   /* 2*D */
#define TEN_D   6.00560980f   /* 10*D */

typedef float v2f __attribute__((ext_vector_type(2)));

__device__ __forceinline__ float fast_exp2(float x) {
#if __has_builtin(__builtin_amdgcn_exp2f)
    return __builtin_amdgcn_exp2f(x);
#else
    float r;
    asm("v_exp_f32 %0, %1" : "=v"(r) : "v"(x));
    return r;
#endif
}
__device__ __forceinline__ float fast_sqrt(float x) {
#if __has_builtin(__builtin_amdgcn_sqrtf)
    return __builtin_amdgcn_sqrtf(x);
#else
    return sqrtf(x);
#endif
}

// sum over each quad (lanes {4q..4q+3}) via two DPP quad_perm swaps — pure VALU,
// no LDS-pipe latency. (Correctness proven in R4.)
__device__ __forceinline__ float quad_sum(float x) {
    int a = __builtin_amdgcn_update_dpp(0, __float_as_int(x), 0xB1, 0xF, 0xF, true); // [1,0,3,2]
    x += __int_as_float(a);
    int b = __builtin_amdgcn_update_dpp(0, __float_as_int(x), 0x4E, 0xF, 0xF, true); // [2,3,0,1]
    x += __int_as_float(b);
    return x;
}

// Core over chunks [C0, C0+NC): full 512-neighbor sweep (8 j per lane),
// geometric chain per chunk, QP scale, DPP quad-reduce, LDS store of
// columns k = 10*C0 .. 10*(C0+NC)-1 into this row's [16][52] matrix.
template <int C0, int NC>
__device__ __forceinline__ void rbf_core(const float* __restrict__ posb, int lane,
                                         float pix, float piy, float piz,
                                         float (*redm_row)[52])
{
    const float E5[5] = {1.0f, 6.73794700e-3f, 4.53999298e-5f,
                         3.05902321e-7f, 2.06115362e-9f};   // e^{-5c}
    v2f acc[NC * 5];
#pragma unroll
    for (int m = 0; m < NC * 5; ++m) acc[m] = (v2f){0.0f, 0.0f};

#pragma unroll
    for (int jj = 0; jj < 8; ++jj) {
        const float* pj = posb + jj * 192 + lane * 3;
        const float dx = pix - pj[0];
        const float dy = piy - pj[1];
        const float dz = piz - pj[2];
        const float d2 = fmaf(dx, dx, fmaf(dy, dy, fmaf(dz, dz, 1e-8f)));
        float dS = fast_sqrt(d2) * S_C;
        dS = fminf(dS, 42.0f);                     // true values identically 0 beyond
        const float Ap = fast_exp2(dS * TWO_DS);   // 2^{2D*dS} <= 2^50.5

#pragma unroll
        for (int ci = 0; ci < NC; ++ci) {
            const int c = C0 + ci;
            const float u  = dS - (float)c * TEN_D;
            const float t0 = fast_exp2(-(u * u));
            const float Ac = Ap * E5[c];
            const float M  = Ac * Ac;              // <= 2^101, finite
            v2f g = {t0, t0 * Ac};
            acc[ci * 5 + 0] += g;
            const v2f Mv = {M, M};
#pragma unroll
            for (int t = 1; t < 5; ++t) {
                g = g * Mv;
                acc[ci * 5 + t] += g;
            }
        }
    }

    // j-independent e^{-r^2/4} factors (r = 2t, 2t+1), then quad pre-reduce + store
    const v2f QP[5] = {{1.0f,            0.778800783f},
                       {0.367879441f,    0.105399225f},
                       {1.83156389e-2f,  1.93045414e-3f},
                       {1.23409804e-4f,  4.78511739e-6f},
                       {1.12535175e-7f,  1.60522806e-9f}};
    const bool writer = (lane & 3) == 0;
    const int  q      = lane >> 2;
#pragma unroll
    for (int m = 0; m < NC * 5; ++m) {
        v2f v = acc[m] * QP[m % 5];
        v.x = quad_sum(v.x);
        v.y = quad_sum(v.y);
        if (writer) {
            const int col = 10 * C0 + (m / 5) * 10 + (m % 5) * 2;
            *reinterpret_cast<v2f*>(&redm_row[q][col]) = v;   // 8B-aligned
        }
    }
}

// 2 rows per block; 2 waves per row splitting k (role 0: k0..29, role 1: k30..49).
// Accumulator state <= 30 VGPR -> target <=64 total => 8 waves/SIMD.
__global__ __launch_bounds__(256, 8)
void rbf_mean_kernel(const float* __restrict__ pos,
                     float* __restrict__ meanout)
{
    __shared__ float redm[2][16][52];   // [rowLocal][quad][k] (+pad)  6.5 KB

    const int w     = threadIdx.x >> 6;
    const int lane  = threadIdx.x & 63;
    const int rloc  = w >> 1;               // 0..1
    const int role  = w & 1;                // 0: chunks 0-2, 1: chunks 3-4
    const int row   = blockIdx.x * 2 + rloc;    // 0..8191
    const int b     = row >> 9;             // N = 512
    const int i     = row & 511;

    const float* posb = pos + (size_t)b * 1536;

    const int i3 = __builtin_amdgcn_readfirstlane(3 * i);   // wave-uniform
    const float pix = posb[i3 + 0];
    const float piy = posb[i3 + 1];
    const float piz = posb[i3 + 2];

    if (role == 0) rbf_core<0, 3>(posb, lane, pix, piy, piz, redm[rloc]);
    else           rbf_core<3, 2>(posb, lane, pix, piy, piz, redm[rloc]);

    __syncthreads();

    // wave w sums 25 columns of its row: cols role*25 .. role*25+24
    if (lane < 25) {
        const int col = role * 25 + lane;
        const float* base = &redm[rloc][0][col];
        float s0 = 0.f, s1 = 0.f, s2 = 0.f, s3 = 0.f;
#pragma unroll
        for (int r = 0; r < 16; r += 4) {
            s0 += base[(r + 0) * 52];
            s1 += base[(r + 1) * 52];
            s2 += base[(r + 2) * 52];
            s3 += base[(r + 3) * 52];
        }
        meanout[(size_t)row * 50 + col] = ((s0 + s1) + (s2 + s3)) * (1.0f / 512.0f);
    }
}

// out[row][:] = te[an[row]][:] + pb[:] + mean[row][:] @ pw   (R2-proven)
__global__ __launch_bounds__(256)
void proj_kernel(const float* __restrict__ mean,
                 const int* __restrict__ an,
                 const float* __restrict__ te,
                 const float* __restrict__ pw,
                 const float* __restrict__ pb,
                 float* __restrict__ out)
{
    const int w    = threadIdx.x >> 6;
    const int lane = threadIdx.x & 63;
    int wid = blockIdx.x * 4 + w;                       // 0..2047
    wid = __builtin_amdgcn_readfirstlane(wid);          // force SGPR
    const int row0 = wid * 4;

    const float4 bias = reinterpret_cast<const float4*>(pb)[lane];
    float4 o[4];
#pragma unroll
    for (int r = 0; r < 4; ++r) {
        const int tok = an[row0 + r];                   // wave-uniform
        const float4 t = reinterpret_cast<const float4*>(te + (size_t)tok * 256)[lane];
        o[r].x = bias.x + t.x; o[r].y = bias.y + t.y;
        o[r].z = bias.z + t.z; o[r].w = bias.w + t.w;
    }
#pragma unroll
    for (int k = 0; k < 50; ++k) {
        const float4 w4 = reinterpret_cast<const float4*>(pw + (size_t)k * 256)[lane];
#pragma unroll
        for (int r = 0; r < 4; ++r) {
            const float mk = mean[(size_t)(row0 + r) * 50 + k];  // wave-uniform
            o[r].x = fmaf(mk, w4.x, o[r].x);
            o[r].y = fmaf(mk, w4.y, o[r].y);
            o[r].z = fmaf(mk, w4.z, o[r].z);
            o[r].w = fmaf(mk, w4.w, o[r].w);
        }
    }
#pragma unroll
    for (int r = 0; r < 4; ++r)
        reinterpret_cast<float4*>(out)[(size_t)(row0 + r) * 64 + lane] = o[r];
}

// ---- fallback fused kernel (only if d_ws is too small; R5-proven) ----
__global__ __launch_bounds__(256)
void rbf_fused_fallback(const float* __restrict__ pos,
                        const int* __restrict__ an,
                        const float* __restrict__ te,
                        const float* __restrict__ pw,
                        const float* __restrict__ pb,
                        float* __restrict__ out)
{
    __shared__ float redm[4][16][52];
    __shared__ float ms[4][52];

    const int w    = threadIdx.x >> 6;
    const int lane = threadIdx.x & 63;
    const int row  = blockIdx.x * 4 + w;
    const int b    = row >> 9;
    const int i    = row & 511;
    const float* posb = pos + (size_t)b * 1536;

    const int i3 = __builtin_amdgcn_readfirstlane(3 * i);
    const float pix = posb[i3 + 0];
    const float piy = posb[i3 + 1];
    const float piz = posb[i3 + 2];

    rbf_core<0, 5>(posb, lane, pix, piy, piz, redm[w]);

    if (lane < 50) {
        const float* base = &redm[w][0][lane];
        float s = 0.f;
#pragma unroll
        for (int r = 0; r < 16; ++r) s += base[r * 52];
        ms[w][lane] = s * (1.0f / 512.0f);
    }

    const int tok = an[row];
    float4 o = reinterpret_cast<const float4*>(pb)[lane];
    const float4 t = reinterpret_cast<const float4*>(te + (size_t)tok * 256)[lane];
    o.x += t.x; o.y += t.y; o.z += t.z; o.w += t.w;
#pragma unroll
    for (int k = 0; k < 50; ++k) {
        const float mk = ms[w][k];
        const float4 w4 = reinterpret_cast<const float4*>(pw + k * 256)[lane];
        o.x = fmaf(mk, w4.x, o.x);
        o.y = fmaf(mk, w4.y, o.y);
        o.z = fmaf(mk, w4.z, o.z);
        o.w = fmaf(mk, w4.w, o.w);
    }
    reinterpret_cast<float4*>(out)[(size_t)row * 64 + lane] = o;
}

extern "C" void kernel_launch(void* const* d_in, const int* in_sizes, int n_in,
                              void* d_out, int out_size, void* d_ws, size_t ws_size,
                              hipStream_t stream)
{
    const int*   an  = (const int*)  d_in[0];   // [16,512] int32
    const float* pos = (const float*)d_in[1];   // [16,512,3]
    const float* te  = (const float*)d_in[2];   // [100,256]
    const float* pw  = (const float*)d_in[3];   // [50,256]
    const float* pb  = (const float*)d_in[4];   // [256]
    float* out = (float*)d_out;                  // [16,512,256]

    const size_t mean_bytes = (size_t)8192 * 50 * sizeof(float);
    if (ws_size >= mean_bytes) {
        float* mean = (float*)d_ws;
        rbf_mean_kernel<<<4096, 256, 0, stream>>>(pos, mean);
        proj_kernel<<<512, 256, 0, stream>>>(mean, an, te, pw, pb, out);
    } else {
        rbf_fused_fallback<<<2048, 256, 0, stream>>>(pos, an, te, pw, pb, out);
    }
}

// Round 9
// 27.318 us; speedup vs baseline: 1.9477x; 1.0510x over previous
//
#include <hip/hip_runtime.h>

// ---- problem constants ----
// B=16, N=512, D_MODEL=256, NUM_RBF=50, CUTOFF=12
// delta = 12/49, width = 2*delta
// S = 2.45229158;  D = delta*S = sqrt(log2 e)/2 = 0.60056098
// Key identity: 4*D^2 = log2(e)  =>  2^{-m*D^2} = e^{-m/4}
// g_k (k = 10c + r): u = dS - 10c*D;  g = 2^{-u^2} * Ac^r * e^{-r^2/4}
// Ac = Ap * e^{-5c}, Ap = 2^{2D*dS}. Pure geometric chain per chunk,
// e^{-r^2/4} applied once at the end (j-independent).
#define S_C     2.45229158f
#define TWO_DS  1.20112241f   /* 2*D */
#define TEN_D   6.00560980f   /* 10*D */
#define E5_1 6.73794700e-3f   /* e^-5  */
#define E5_2 4.53999298e-5f   /* e^-10 */
#define E5_3 3.05902321e-7f   /* e^-15 */
#define E5_4 2.06115362e-9f   /* e^-20 */

typedef float v2f __attribute__((ext_vector_type(2)));

__device__ __forceinline__ float fast_exp2(float x) {
#if __has_builtin(__builtin_amdgcn_exp2f)
    return __builtin_amdgcn_exp2f(x);
#else
    float r;
    asm("v_exp_f32 %0, %1" : "=v"(r) : "v"(x));
    return r;
#endif
}
__device__ __forceinline__ float fast_sqrt(float x) {
#if __has_builtin(__builtin_amdgcn_sqrtf)
    return __builtin_amdgcn_sqrtf(x);
#else
    return sqrtf(x);
#endif
}

// R6 counters showed the compiler lowers v2f arithmetic to 2x scalar VALU.
// Force VOP3P packed-f32 (gfx90a+/CDNA4): one instruction per 2 lanes-of-k.
__device__ __forceinline__ v2f pk_mul(v2f a, v2f b) {
    v2f d;
    asm("v_pk_mul_f32 %0, %1, %2" : "=v"(d) : "v"(a), "v"(b));
    return d;
}
__device__ __forceinline__ v2f pk_add(v2f a, v2f b) {
    v2f d;
    asm("v_pk_add_f32 %0, %1, %2" : "=v"(d) : "v"(a), "v"(b));
    return d;
}

// One wave per output row (b,i). Lanes split the 512 neighbors (8 each).
// EXACT R2 structure (best known: 26.6 us) — only change: packed chain + QP.
template <bool FUSED>
__global__ __launch_bounds__(256)
void rbf_mean_kernel(const float* __restrict__ pos,
                     float* __restrict__ meanout,   // !FUSED
                     const int* __restrict__ an,    // FUSED only
                     const float* __restrict__ te,
                     const float* __restrict__ pw,
                     const float* __restrict__ pb,
                     float* __restrict__ out)
{
    __shared__ v2f red2[4][32 * 25];   // [wave][(lane/2)*25 + m]
    __shared__ float ms[4][52];

    const int w    = threadIdx.x >> 6;
    const int lane = threadIdx.x & 63;
    const int row  = blockIdx.x * 4 + w;    // 0..8191
    const int b    = row >> 9;              // N = 512
    const int i    = row & 511;

    const float* posb = pos + (size_t)b * 1536;

    // preload this lane's 8 neighbor positions
    float jx[8], jy[8], jz[8];
#pragma unroll
    for (int jj = 0; jj < 8; ++jj) {
        const int j = jj * 64 + lane;
        jx[jj] = posb[j * 3 + 0];
        jy[jj] = posb[j * 3 + 1];
        jz[jj] = posb[j * 3 + 2];
    }
    const float pix = posb[i * 3 + 0];
    const float piy = posb[i * 3 + 1];
    const float piz = posb[i * 3 + 2];

    v2f acc[25];   // acc[5c+t] = sum_j {t''_{2t}, t''_{2t+1}} of chunk c
#pragma unroll
    for (int m = 0; m < 25; ++m) acc[m] = (v2f){0.0f, 0.0f};

#pragma unroll
    for (int jj = 0; jj < 8; ++jj) {
        const float dx = pix - jx[jj];
        const float dy = piy - jy[jj];
        const float dz = piz - jz[jj];
        const float d2 = fmaf(dx, dx, fmaf(dy, dy, fmaf(dz, dz, 1e-8f)));
        float dS = fast_sqrt(d2) * S_C;
        dS = fminf(dS, 42.0f);            // true values identically 0 beyond
        const float Ap = fast_exp2(dS * TWO_DS);   // 2^{2D*dS} <= 2^50.5

#pragma unroll
        for (int c = 0; c < 5; ++c) {
            const float u  = dS - (float)c * TEN_D;
            const float t0 = fast_exp2(-(u * u));
            const float Ac  = (c == 0) ? Ap :
                              (c == 1) ? Ap * E5_1 :
                              (c == 2) ? Ap * E5_2 :
                              (c == 3) ? Ap * E5_3 : Ap * E5_4;
            const float Ac2 = Ac * Ac;    // <= 2^101, finite
            v2f g = {t0, t0 * Ac};
            acc[5 * c + 0] = pk_add(acc[5 * c + 0], g);
            const v2f M = {Ac2, Ac2};
#pragma unroll
            for (int t = 1; t < 5; ++t) {
                g = pk_mul(g, M);
                acc[5 * c + t] = pk_add(acc[5 * c + t], g);
            }
        }
    }

    // j-independent e^{-r^2/4} factors (r = 2t, 2t+1)
    {
        const v2f QP[5] = {{1.0f,            0.778800783f},
                           {0.367879441f,    0.105399225f},
                           {1.83156389e-2f,  1.93045414e-3f},
                           {1.23409804e-4f,  4.78511739e-6f},
                           {1.12535175e-7f,  1.60522806e-9f}};
#pragma unroll
        for (int m = 0; m < 25; ++m) acc[m] = pk_mul(acc[m], QP[m % 5]);
    }

    // pair-reduce via shfl_xor(1); even lanes write the 32x25-v2f LDS matrix
#pragma unroll
    for (int m = 0; m < 25; ++m) {
        const float lx = __shfl_xor(acc[m].x, 1);
        const float ly = __shfl_xor(acc[m].y, 1);
        acc[m] = pk_add(acc[m], (v2f){lx, ly});
    }
    if ((lane & 1) == 0) {
        v2f* myrow = &red2[w][(lane >> 1) * 25];
#pragma unroll
        for (int m = 0; m < 25; ++m) myrow[m] = acc[m];
    }
    __syncthreads();

    float meanv = 0.0f;
    if (lane < 50) {
        const float* col = (const float*)&red2[w][0] + lane;
        float s0 = 0.f, s1 = 0.f, s2 = 0.f, s3 = 0.f;
#pragma unroll
        for (int r = 0; r < 32; r += 4) {
            s0 += col[(r + 0) * 50];
            s1 += col[(r + 1) * 50];
            s2 += col[(r + 2) * 50];
            s3 += col[(r + 3) * 50];
        }
        meanv = ((s0 + s1) + (s2 + s3)) * (1.0f / 512.0f);
    }

    if constexpr (!FUSED) {
        if (lane < 50) meanout[(size_t)row * 50 + lane] = meanv;
    } else {
        if (lane < 50) ms[w][lane] = meanv;
        __syncthreads();

        const int tok = an[row];
        float4 o = reinterpret_cast<const float4*>(pb)[lane];
        const float4 t = reinterpret_cast<const float4*>(te + (size_t)tok * 256)[lane];
        o.x += t.x; o.y += t.y; o.z += t.z; o.w += t.w;
#pragma unroll
        for (int k = 0; k < 50; ++k) {
            const float mk = ms[w][k];
            const float4 w4 = reinterpret_cast<const float4*>(pw + k * 256)[lane];
            o.x = fmaf(mk, w4.x, o.x);
            o.y = fmaf(mk, w4.y, o.y);
            o.z = fmaf(mk, w4.z, o.z);
            o.w = fmaf(mk, w4.w, o.w);
        }
        reinterpret_cast<float4*>(out)[(size_t)row * 64 + lane] = o;
    }
}

// out[row][:] = te[an[row]][:] + pb[:] + mean[row][:] @ pw   (R2-exact)
__global__ __launch_bounds__(256)
void proj_kernel(const float* __restrict__ mean,
                 const int* __restrict__ an,
                 const float* __restrict__ te,
                 const float* __restrict__ pw,
                 const float* __restrict__ pb,
                 float* __restrict__ out)
{
    const int w    = threadIdx.x >> 6;
    const int lane = threadIdx.x & 63;
    int wid = blockIdx.x * 4 + w;                       // 0..2047
    wid = __builtin_amdgcn_readfirstlane(wid);          // force SGPR
    const int row0 = wid * 4;

    const float4 bias = reinterpret_cast<const float4*>(pb)[lane];
    float4 o[4];
#pragma unroll
    for (int r = 0; r < 4; ++r) {
        const int tok = an[row0 + r];                   // wave-uniform
        const float4 t = reinterpret_cast<const float4*>(te + (size_t)tok * 256)[lane];
        o[r].x = bias.x + t.x; o[r].y = bias.y + t.y;
        o[r].z = bias.z + t.z; o[r].w = bias.w + t.w;
    }
#pragma unroll
    for (int k = 0; k < 50; ++k) {
        const float4 w4 = reinterpret_cast<const float4*>(pw + (size_t)k * 256)[lane];
#pragma unroll
        for (int r = 0; r < 4; ++r) {
            const float mk = mean[(size_t)(row0 + r) * 50 + k];  // wave-uniform
            o[r].x = fmaf(mk, w4.x, o[r].x);
            o[r].y = fmaf(mk, w4.y, o[r].y);
            o[r].z = fmaf(mk, w4.z, o[r].z);
            o[r].w = fmaf(mk, w4.w, o[r].w);
        }
    }
#pragma unroll
    for (int r = 0; r < 4; ++r)
        reinterpret_cast<float4*>(out)[(size_t)(row0 + r) * 64 + lane] = o[r];
}

extern "C" void kernel_launch(void* const* d_in, const int* in_sizes, int n_in,
                              void* d_out, int out_size, void* d_ws, size_t ws_size,
                              hipStream_t stream)
{
    const int*   an  = (const int*)  d_in[0];   // [16,512] int32
    const float* pos = (const float*)d_in[1];   // [16,512,3]
    const float* te  = (const float*)d_in[2];   // [100,256]
    const float* pw  = (const float*)d_in[3];   // [50,256]
    const float* pb  = (const float*)d_in[4];   // [256]
    float* out = (float*)d_out;                  // [16,512,256]

    const size_t mean_bytes = (size_t)8192 * 50 * sizeof(float);
    if (ws_size >= mean_bytes) {
        float* mean = (float*)d_ws;
        rbf_mean_kernel<false><<<2048, 256, 0, stream>>>(pos, mean, nullptr, nullptr,
                                                         nullptr, nullptr, nullptr);
        proj_kernel<<<512, 256, 0, stream>>>(mean, an, te, pw, pb, out);
    } else {
        rbf_mean_kernel<true><<<2048, 256, 0, stream>>>(pos, nullptr, an, te, pw, pb, out);
    }
}